// Round 4
// baseline (70.651 us; speedup 1.0000x reference)
//
#include <hip/hip_runtime.h>

// WindowEmbedding: x[B,T,D] fp32 -> out[B,T,D*W], slot w = x shifted left by w,
// zero past sequence end. B=16, T=2048, D=512, W=5.
//
// out[(b,t)] row (640 f4) = contiguous x slice starting at (b,t), zero-guarded
// at the sequence end. Rolling-register window: each thread keeps 5 rows'
// worth (its lane's f4) in registers; per output row: 1 load + 5 stores
// instead of 5 loads + 5 stores. Read amp (R+4)/R = 1.0625 at R=64.

typedef float f4 __attribute__((ext_vector_type(4)));

constexpr int T_DIM = 2048;
constexpr int D4 = 128;            // 512 floats / 4 per float4
constexpr int W = 5;
constexpr int R = 64;              // rows per block (two 128-thread halves x 32)
constexpr int HR = R / 2;          // rows per half
constexpr int ROW_OUT = W * D4;    // 640 f4 per output row

__global__ __launch_bounds__(256) void window_embed_kernel(
    const f4* __restrict__ x, f4* __restrict__ out) {
  const int tid  = threadIdx.x;
  const int lane = tid & 127;      // f4 index within a D-row
  const int half = tid >> 7;       // which 32-row sub-chunk

  const int tbase = blockIdx.x * R + half * HR;          // first t of my chunk
  const long long row0 = (long long)blockIdx.y * T_DIM + tbase;

  const f4* __restrict__ xb = x + row0 * D4 + lane;
  f4* __restrict__ ob = out + row0 * (long long)ROW_OUT + lane;

  const f4 zero = (f4)0.f;

  // Prime the 5-row rolling window: win[q] holds x row (tbase+q) at my lane.
  f4 win[W];
#pragma unroll
  for (int q = 0; q < W; ++q)
    win[q] = (tbase + q < T_DIM) ? xb[q * D4] : zero;

  // Invariant before iter i: win[(i+w)%5] == x row (tbase+i+w), w=0..4.
#pragma unroll
  for (int i = 0; i < HR; ++i) {
#pragma unroll
    for (int w = 0; w < W; ++w) {
      __builtin_nontemporal_store(win[(i + w) % W],
                                  &ob[(long long)i * ROW_OUT + w * D4]);
    }
    // Refill slot i%5 with row tbase+i+5 (consumed 5 iterations later).
    if (i < HR - 1 || true) {
      win[i % W] = (tbase + i + W < T_DIM) ? xb[(i + W) * D4] : zero;
    }
  }
}

extern "C" void kernel_launch(void* const* d_in, const int* in_sizes, int n_in,
                              void* d_out, int out_size, void* d_ws, size_t ws_size,
                              hipStream_t stream) {
  const f4* x = (const f4*)d_in[0];
  f4* out = (f4*)d_out;

  dim3 grid(T_DIM / R, 16);   // (32, 16) = 512 blocks
  window_embed_kernel<<<grid, 256, 0, stream>>>(x, out);
}